// Round 4
// baseline (17442.439 us; speedup 1.0000x reference)
//
#include <hip/hip_runtime.h>

// LP via PDHG. A: (4094, 16384) row-major fp32; b, c: (16384,) fp32. Out: scalar fp32.
// Round 4: single fp16 transposed copy AT16 (M_COLS x NPAD, 134.2 MB). Whole solve
// (power iteration + PDHG) runs off AT16 only -> working set < 256 MiB Infinity
// Cache -> A-traffic becomes L3-resident instead of HBM-streaming.
//   A^T u : k_col (one wave per column, fused x/z update in PDHG)
//   A z   : k_az_partial (64-col chunks, 512 blocks) + k_y_update (reduce 256 partials)
// fp32 fallback kept if ws too small.

constexpr int N_ROWS = 4094;       // N_NODES - 2
constexpr int NPAD   = 4096;       // padded row count for AT
constexpr int M_COLS = 16384;      // M_EDGES
constexpr int M4     = M_COLS / 4;
constexpr int PDHG_ITERS  = 300;
constexpr int POWER_ITERS = 20;
// fp32 fallback chunking
constexpr int P_CHUNKS = 64;
constexpr int ROWS_PER_CHUNK = 64;
// A z chunking over columns
constexpr int AZ_J  = 64;          // columns per chunk
constexpr int AZ_CH = M_COLS / AZ_J; // 256 chunks

typedef _Float16 half8 __attribute__((ext_vector_type(8)));
typedef _Float16 half_t;

// ---------------- init: x=0, v=1/128, y=t=0 (full 4096 incl. pads) ----------------
__global__ __launch_bounds__(256) void k_init(float* __restrict__ x,
                                              float* __restrict__ v,
                                              float* __restrict__ y,
                                              float* __restrict__ t) {
    int j = blockIdx.x * 256 + threadIdx.x;
    if (j < M_COLS) { x[j] = 0.f; v[j] = 0.0078125f; }
    if (j < NPAD) { y[j] = 0.f; t[j] = 0.f; }
}

// ---------------- A (fp32, N_ROWS x M_COLS) -> AT16 (fp16, M_COLS x NPAD, pad rows = 0) ----
__global__ __launch_bounds__(256) void k_transpose(const float* __restrict__ A,
                                                   half_t* __restrict__ AT) {
    __shared__ float tile[64][65];
    const int i0 = blockIdx.x * 64;   // source row tile
    const int j0 = blockIdx.y * 64;   // source col tile
    const int t = threadIdx.x;
    const float4* __restrict__ A4 = reinterpret_cast<const float4*>(A);
#pragma unroll
    for (int k = 0; k < 4; ++k) {
        int idx = k * 256 + t;        // 0..1023
        int r = idx >> 4, c4 = idx & 15;
        int i = i0 + r;
        float4 val = (i < N_ROWS) ? A4[((size_t)i * M_COLS + j0) / 4 + c4]
                                  : make_float4(0.f, 0.f, 0.f, 0.f);
        tile[r][c4 * 4 + 0] = val.x;
        tile[r][c4 * 4 + 1] = val.y;
        tile[r][c4 * 4 + 2] = val.z;
        tile[r][c4 * 4 + 3] = val.w;
    }
    __syncthreads();
    half8* __restrict__ O8 = reinterpret_cast<half8*>(AT);
#pragma unroll
    for (int k = 0; k < 2; ++k) {
        int idx = k * 256 + t;        // 0..511
        int j = idx >> 3, q = idx & 7;
        half8 h;
#pragma unroll
        for (int e = 0; e < 8; ++e) h[e] = (half_t)tile[q * 8 + e][j];
        O8[((size_t)(j0 + j) * NPAD + i0) / 8 + q] = h;
    }
}

// ---------------- column dot over AT rows: one wave per column j ----------------
// MODE 0: w[j] = dot(AT_j, u)
// MODE 1: g = dot(AT_j, u); xn = clip(x - tau*(c+g), 0, b); z = 2xn - x; x = xn
template <int MODE>
__global__ __launch_bounds__(256) void k_col(const half_t* __restrict__ AT,
                                             const float* __restrict__ u,
                                             const float* __restrict__ c,
                                             const float* __restrict__ b,
                                             float* __restrict__ x,
                                             float* __restrict__ z,
                                             float* __restrict__ w,
                                             const float* __restrict__ scalars) {
    const int wv   = threadIdx.x >> 6;
    const int lane = threadIdx.x & 63;
    const int j = blockIdx.x * 4 + wv;
    const half8* __restrict__ row = reinterpret_cast<const half8*>(AT + (size_t)j * NPAD);
    const float4* __restrict__ u4 = reinterpret_cast<const float4*>(u);
    float s = 0.f;
#pragma unroll
    for (int it = 0; it < NPAD / 8 / 64; ++it) {  // 8 iters
        int k = it * 64 + lane;
        half8 a = row[k];
        float4 ua = u4[2 * k];
        float4 ub = u4[2 * k + 1];
        s = fmaf((float)a[0], ua.x, s);
        s = fmaf((float)a[1], ua.y, s);
        s = fmaf((float)a[2], ua.z, s);
        s = fmaf((float)a[3], ua.w, s);
        s = fmaf((float)a[4], ub.x, s);
        s = fmaf((float)a[5], ub.y, s);
        s = fmaf((float)a[6], ub.z, s);
        s = fmaf((float)a[7], ub.w, s);
    }
#pragma unroll
    for (int o = 32; o > 0; o >>= 1) s += __shfl_down(s, o, 64);
    if (lane == 0) {
        if (MODE == 0) {
            w[j] = s;
        } else {
            float tau = scalars[1];
            float xo = x[j];
            float xn = xo - tau * (c[j] + s);
            xn = fminf(fmaxf(xn, 0.f), b[j]);
            x[j] = xn;
            z[j] = 2.f * xn - xo;
        }
    }
}

// ---------------- A z via AT: partial[ch][i] = sum_{j in ch} AT[j][i] * z[j] ----------------
// grid (NPAD/8/256 = 2, AZ_CH = 256) -> 512 blocks
__global__ __launch_bounds__(256) void k_az_partial(const half_t* __restrict__ AT,
                                                    const float* __restrict__ zv,
                                                    float* __restrict__ partial) {
    const int ch = blockIdx.y;
    const int j0 = ch * AZ_J;
    const int i8 = blockIdx.x * 256 + threadIdx.x;   // half8 index over i: 0..511
    __shared__ float sz[AZ_J];
    if (threadIdx.x < AZ_J) sz[threadIdx.x] = zv[j0 + threadIdx.x];
    __syncthreads();
    const half8* __restrict__ A8 = reinterpret_cast<const half8*>(AT);
    float acc[8];
#pragma unroll
    for (int q = 0; q < 8; ++q) acc[q] = 0.f;
    for (int jj = 0; jj < AZ_J; ++jj) {
        half8 a = A8[(size_t)(j0 + jj) * (NPAD / 8) + i8];
        float zj = sz[jj];
#pragma unroll
        for (int q = 0; q < 8; ++q) acc[q] = fmaf((float)a[q], zj, acc[q]);
    }
    float4* __restrict__ P4 = reinterpret_cast<float4*>(partial + (size_t)ch * NPAD);
    P4[2 * i8]     = make_float4(acc[0], acc[1], acc[2], acc[3]);
    P4[2 * i8 + 1] = make_float4(acc[4], acc[5], acc[6], acc[7]);
}

// ---------------- reduce partials over AZ_CH chunks: MODE 0: out=s ; MODE 1: out += sigma*s ----
template <int MODE>
__global__ __launch_bounds__(256) void k_y_update(const float* __restrict__ partial,
                                                  float* __restrict__ out,
                                                  const float* __restrict__ scalars) {
    int i = blockIdx.x * 256 + threadIdx.x;     // 0..4095
    float s = 0.f;
    for (int p = 0; p < AZ_CH; ++p) s += partial[(size_t)p * NPAD + i];
    if (MODE == 0) out[i] = s;
    else           out[i] += scalars[1] * s;
}

// ================= fp32 fallback kernels =================
__global__ __launch_bounds__(256) void k_at_partial(const float* __restrict__ A,
                                                    const float* __restrict__ u,
                                                    float* __restrict__ partial) {
    const int j4 = blockIdx.x * 256 + threadIdx.x;
    const int r0 = blockIdx.y * ROWS_PER_CHUNK;
    const int r1 = min(r0 + ROWS_PER_CHUNK, N_ROWS);
    __shared__ float su[ROWS_PER_CHUNK];
    if (threadIdx.x < (unsigned)(r1 - r0)) su[threadIdx.x] = u[r0 + threadIdx.x];
    __syncthreads();
    const float4* __restrict__ A4 = reinterpret_cast<const float4*>(A);
    float4 acc = make_float4(0.f, 0.f, 0.f, 0.f);
    for (int i = r0; i < r1; ++i) {
        const float ui = su[i - r0];
        float4 a = A4[(size_t)i * M4 + j4];
        acc.x = fmaf(a.x, ui, acc.x);
        acc.y = fmaf(a.y, ui, acc.y);
        acc.z = fmaf(a.z, ui, acc.z);
        acc.w = fmaf(a.w, ui, acc.w);
    }
    reinterpret_cast<float4*>(partial)[(size_t)blockIdx.y * M4 + j4] = acc;
}

__global__ __launch_bounds__(256) void k_reduce_w(const float* __restrict__ partial,
                                                  float* __restrict__ w) {
    int j = blockIdx.x * 256 + threadIdx.x;
    float s = 0.f;
    for (int p = 0; p < P_CHUNKS; ++p) s += partial[(size_t)p * M_COLS + j];
    w[j] = s;
}

__global__ __launch_bounds__(256) void k_x_update(const float* __restrict__ partial,
                                                  const float* __restrict__ c,
                                                  const float* __restrict__ b,
                                                  float* __restrict__ x,
                                                  float* __restrict__ z,
                                                  const float* __restrict__ scalars) {
    int j = blockIdx.x * 256 + threadIdx.x;
    const float tau = scalars[1];
    float s = 0.f;
    for (int p = 0; p < P_CHUNKS; ++p) s += partial[(size_t)p * M_COLS + j];
    float xo = x[j];
    float xn = xo - tau * (c[j] + s);
    xn = fminf(fmaxf(xn, 0.f), b[j]);
    x[j] = xn;
    z[j] = 2.f * xn - xo;
}

template <int MODE>
__global__ __launch_bounds__(256) void k_row_dot(const float* __restrict__ A,
                                                 const float* __restrict__ vec,
                                                 float* __restrict__ out,
                                                 const float* __restrict__ scalars) {
    const int i = blockIdx.x;
    const float4* __restrict__ row = reinterpret_cast<const float4*>(A + (size_t)i * M_COLS);
    const float4* __restrict__ v4  = reinterpret_cast<const float4*>(vec);
    float s = 0.f;
    for (int k = threadIdx.x; k < M4; k += 256) {
        float4 a = row[k];
        float4 v = v4[k];
        s = fmaf(a.x, v.x, s);
        s = fmaf(a.y, v.y, s);
        s = fmaf(a.z, v.z, s);
        s = fmaf(a.w, v.w, s);
    }
    for (int o = 32; o > 0; o >>= 1) s += __shfl_down(s, o, 64);
    __shared__ float sm[4];
    if ((threadIdx.x & 63) == 0) sm[threadIdx.x >> 6] = s;
    __syncthreads();
    if (threadIdx.x == 0) {
        float t = sm[0] + sm[1] + sm[2] + sm[3];
        if (MODE == 0) out[i] = t;
        else           out[i] += scalars[1] * t;
    }
}

// ---------------- shared small kernels ----------------
template <int MODE>
__global__ __launch_bounds__(1024) void k_norm(const float* __restrict__ w,
                                               float* __restrict__ scalars) {
    const float4* __restrict__ w4 = reinterpret_cast<const float4*>(w);
    float s = 0.f;
    for (int k = threadIdx.x; k < M4; k += 1024) {
        float4 a = w4[k];
        s = fmaf(a.x, a.x, s);
        s = fmaf(a.y, a.y, s);
        s = fmaf(a.z, a.z, s);
        s = fmaf(a.w, a.w, s);
    }
    for (int o = 32; o > 0; o >>= 1) s += __shfl_down(s, o, 64);
    __shared__ float sm[16];
    if ((threadIdx.x & 63) == 0) sm[threadIdx.x >> 6] = s;
    __syncthreads();
    if (threadIdx.x == 0) {
        float t = 0.f;
        for (int q = 0; q < 16; ++q) t += sm[q];
        float nrm = sqrtf(t);
        if (MODE == 0) scalars[0] = nrm;
        else           scalars[1] = 0.9f / sqrtf(nrm);
    }
}

__global__ __launch_bounds__(256) void k_scale(const float* __restrict__ w,
                                               float* __restrict__ v,
                                               const float* __restrict__ scalars) {
    int j = blockIdx.x * 256 + threadIdx.x;
    v[j] = w[j] / scalars[0];
}

__global__ __launch_bounds__(1024) void k_obj(const float* __restrict__ x,
                                              const float* __restrict__ c,
                                              float* __restrict__ out) {
    float s = 0.f;
    for (int k = threadIdx.x; k < M_COLS; k += 1024) s = fmaf(x[k], -c[k], s);
    for (int o = 32; o > 0; o >>= 1) s += __shfl_down(s, o, 64);
    __shared__ float sm[16];
    if ((threadIdx.x & 63) == 0) sm[threadIdx.x >> 6] = s;
    __syncthreads();
    if (threadIdx.x == 0) {
        float t = 0.f;
        for (int q = 0; q < 16; ++q) t += sm[q];
        out[0] = t;
    }
}

extern "C" void kernel_launch(void* const* d_in, const int* in_sizes, int n_in,
                              void* d_out, int out_size, void* d_ws, size_t ws_size,
                              hipStream_t stream) {
    const float* A = (const float*)d_in[0];
    const float* b = (const float*)d_in[1];
    const float* c = (const float*)d_in[2];
    float* out = (float*)d_out;

    float* ws = (float*)d_ws;
    float* x       = ws;                        // M
    float* z       = x + M_COLS;                // M
    float* v       = z + M_COLS;                // M
    float* w       = v + M_COLS;                // M
    float* y       = w + M_COLS;                // NPAD
    float* t       = y + NPAD;                  // NPAD
    float* scalars = t + NPAD;                  // 16
    float* partial = scalars + 16;              // 4 MB: max(AZ_CH*NPAD, P_CHUNKS*M_COLS) floats

    size_t partial_floats = (size_t)P_CHUNKS * M_COLS; // 1M floats == AZ_CH*NPAD
    size_t base = (size_t)(partial - ws) * 4 + partial_floats * 4;  // bytes used so far
    size_t at_off = (base + 255) & ~(size_t)255;
    half_t* AT16 = (half_t*)((char*)d_ws + at_off);
    size_t at_bytes = (size_t)M_COLS * NPAD * sizeof(half_t);       // 134.2 MB
    size_t need_at   = at_off + at_bytes;                            // ~138.7 MB
    size_t need_fp32 = base;

    dim3 b256(256);
    dim3 gM(M_COLS / 256);          // 64
    dim3 gCol(M_COLS / 4);          // 4096 (4 waves/block, 1 col/wave)
    dim3 gAz(NPAD / 8 / 256, AZ_CH);// (2, 256) = 512 blocks
    dim3 gYU(NPAD / 256);           // 16
    dim3 gRowA(N_ROWS);
    dim3 gTr(64, 256);              // transpose tiles

    k_init<<<gM, b256, 0, stream>>>(x, v, y, t);

    if (ws_size >= need_at) {
        // ======== L3-resident fp16 AT path ========
        k_transpose<<<gTr, b256, 0, stream>>>(A, AT16);

        for (int it = 0; it < POWER_ITERS; ++it) {
            k_az_partial<<<gAz, b256, 0, stream>>>(AT16, v, partial);             // A v chunks
            k_y_update<0><<<gYU, b256, 0, stream>>>(partial, t, scalars);         // t = A v
            k_col<0><<<gCol, b256, 0, stream>>>(AT16, t, c, b, x, z, w, scalars); // w = A^T t
            k_norm<0><<<1, 1024, 0, stream>>>(w, scalars);
            k_scale<<<gM, b256, 0, stream>>>(w, v, scalars);
        }
        k_az_partial<<<gAz, b256, 0, stream>>>(AT16, v, partial);
        k_y_update<0><<<gYU, b256, 0, stream>>>(partial, t, scalars);
        k_col<0><<<gCol, b256, 0, stream>>>(AT16, t, c, b, x, z, w, scalars);
        k_norm<1><<<1, 1024, 0, stream>>>(w, scalars);                            // tau

        for (int it = 0; it < PDHG_ITERS; ++it) {
            k_col<1><<<gCol, b256, 0, stream>>>(AT16, y, c, b, x, z, w, scalars); // x,z update
            k_az_partial<<<gAz, b256, 0, stream>>>(AT16, z, partial);             // A z chunks
            k_y_update<1><<<gYU, b256, 0, stream>>>(partial, y, scalars);         // y += s*Az
        }
    } else if (ws_size >= need_fp32) {
        // ======== fp32 fallback (round-1 verified) ========
        dim3 gAt(M4 / 256, P_CHUNKS);
        for (int it = 0; it < POWER_ITERS; ++it) {
            k_row_dot<0><<<gRowA, b256, 0, stream>>>(A, v, t, scalars);
            k_at_partial<<<gAt, b256, 0, stream>>>(A, t, partial);
            k_reduce_w<<<gM, b256, 0, stream>>>(partial, w);
            k_norm<0><<<1, 1024, 0, stream>>>(w, scalars);
            k_scale<<<gM, b256, 0, stream>>>(w, v, scalars);
        }
        k_row_dot<0><<<gRowA, b256, 0, stream>>>(A, v, t, scalars);
        k_at_partial<<<gAt, b256, 0, stream>>>(A, t, partial);
        k_reduce_w<<<gM, b256, 0, stream>>>(partial, w);
        k_norm<1><<<1, 1024, 0, stream>>>(w, scalars);
        for (int it = 0; it < PDHG_ITERS; ++it) {
            k_at_partial<<<gAt, b256, 0, stream>>>(A, y, partial);
            k_x_update<<<gM, b256, 0, stream>>>(partial, c, b, x, z, scalars);
            k_row_dot<1><<<gRowA, b256, 0, stream>>>(A, z, y, scalars);
        }
    }

    k_obj<<<1, 1024, 0, stream>>>(x, c, out);
}

// Round 5
// 14980.487 us; speedup vs baseline: 1.1643x; 1.1643x over previous
//
#include <hip/hip_runtime.h>

// LP via PDHG. A: (4094, 16384) row-major fp32; b, c: (16384,) fp32. Out: scalar fp32.
// Round 5: single permuted fp16 A^T copy; PDHG iteration = ONE matrix pass:
//   k_fused: per column j: g=<AT_j,y> (y in LDS), x-update, rank-1 z_j*AT_j into
//            block-local y-partial (register accum, LDS merge) -> partial[block]
//   k_y_update<1>: y += sigma * sum_p partial[p]
// Permuted AT layout (per column j, 512 half8s): half8 p (it=p>>6, l=p&63) holds
// slots i = it*512 + sub*256 + l*4 + e  (sub=elem>>2, e=elem&3) -> conflict-free
// LDS reads/writes + coalesced global loads everywhere.
// fp32 fallback kept.

constexpr int N_ROWS = 4094;
constexpr int NPAD   = 4096;
constexpr int M_COLS = 16384;
constexpr int M4     = M_COLS / 4;
constexpr int PDHG_ITERS  = 300;
constexpr int POWER_ITERS = 20;
constexpr int P_CHUNKS = 64;        // fp32 fallback
constexpr int ROWS_PER_CHUNK = 64;  // fp32 fallback
constexpr int FJ = 32;              // columns per fused block
constexpr int FBLOCKS = M_COLS / FJ;       // 512
constexpr int AZ_J  = 64;
constexpr int AZ_CH = M_COLS / AZ_J;       // 256

typedef _Float16 half8 __attribute__((ext_vector_type(8)));
typedef _Float16 half4 __attribute__((ext_vector_type(4)));
typedef _Float16 half_t;

// ---------------- init ----------------
__global__ __launch_bounds__(256) void k_init(float* __restrict__ x,
                                              float* __restrict__ v,
                                              float* __restrict__ y,
                                              float* __restrict__ t) {
    int j = blockIdx.x * 256 + threadIdx.x;
    if (j < M_COLS) { x[j] = 0.f; v[j] = 0.0078125f; }
    if (j < NPAD) { y[j] = 0.f; t[j] = 0.f; }
}

// ---------------- A -> permuted fp16 AT ----------------
// per column j: half4 index h = it*128 + l*2 + sub holds slots i = it*512+sub*256+l*4+e
__global__ __launch_bounds__(256) void k_transpose(const float* __restrict__ A,
                                                   half_t* __restrict__ AT) {
    __shared__ float tile[64][65];
    const int i0 = blockIdx.x * 64;   // row tile base
    const int j0 = blockIdx.y * 64;   // col tile base
    const int t = threadIdx.x;
    const float4* __restrict__ A4 = reinterpret_cast<const float4*>(A);
#pragma unroll
    for (int k = 0; k < 4; ++k) {
        int idx = k * 256 + t;        // 0..1023
        int r = idx >> 4, c4 = idx & 15;
        int i = i0 + r;
        float4 val = (i < N_ROWS) ? A4[(size_t)i * M4 + (j0 >> 2) + c4]
                                  : make_float4(0.f, 0.f, 0.f, 0.f);
        tile[r][c4 * 4 + 0] = val.x;
        tile[r][c4 * 4 + 1] = val.y;
        tile[r][c4 * 4 + 2] = val.z;
        tile[r][c4 * 4 + 3] = val.w;
    }
    __syncthreads();
    const int it_p = i0 >> 9;
    const int sub  = (i0 >> 8) & 1;
    const int l0   = (i0 & 255) >> 2;   // {0,16,32,48}
    half4* __restrict__ O4 = reinterpret_cast<half4*>(AT);
#pragma unroll
    for (int k = 0; k < 4; ++k) {
        int idx = k * 256 + t;        // 0..1023 = 64 j x 16 lofs
        int j = idx >> 4, lofs = idx & 15;
        half4 h;
#pragma unroll
        for (int e = 0; e < 4; ++e) h[e] = (half_t)tile[lofs * 4 + e][j];
        O4[(size_t)(j0 + j) * 1024 + it_p * 128 + (l0 + lofs) * 2 + sub] = h;
    }
}

// ---------------- fused PDHG x-pass + rank-1 accumulate ----------------
__global__ __launch_bounds__(256) void k_fused(const half_t* __restrict__ AT,
                                               const float* __restrict__ y,
                                               const float* __restrict__ c,
                                               const float* __restrict__ b,
                                               float* __restrict__ x,
                                               float* __restrict__ partial,
                                               const float* __restrict__ scalars) {
    __shared__ float yIn[4096];
    __shared__ float ypart[4096];
    const int tid = threadIdx.x;
    const int wv = tid >> 6, lane = tid & 63;
    {
        const float4* __restrict__ y4 = reinterpret_cast<const float4*>(y);
        float4* s4 = reinterpret_cast<float4*>(yIn);
#pragma unroll
        for (int k = 0; k < 4; ++k) s4[k * 256 + tid] = y4[k * 256 + tid];
    }
    __syncthreads();
    const float tau = scalars[1];
    const int j0 = blockIdx.x * FJ + wv * (FJ / 4);  // 8 cols per wave
    const half8* __restrict__ A8 = reinterpret_cast<const half8*>(AT);

    float acc[64];
#pragma unroll
    for (int q = 0; q < 64; ++q) acc[q] = 0.f;

    half8 cur[8], nxt[8];
#pragma unroll
    for (int p = 0; p < 8; ++p) cur[p] = A8[(size_t)j0 * 512 + p * 64 + lane];

    for (int q = 0; q < FJ / 4; ++q) {
        const int j = j0 + q;
        if (q + 1 < FJ / 4) {
#pragma unroll
            for (int p = 0; p < 8; ++p) nxt[p] = A8[(size_t)(j + 1) * 512 + p * 64 + lane];
        }
        float s = 0.f;
#pragma unroll
        for (int p = 0; p < 8; ++p) {
            const float4 ya = *reinterpret_cast<const float4*>(&yIn[p * 512 + lane * 4]);
            const float4 yb = *reinterpret_cast<const float4*>(&yIn[p * 512 + 256 + lane * 4]);
            s = fmaf((float)cur[p][0], ya.x, s);
            s = fmaf((float)cur[p][1], ya.y, s);
            s = fmaf((float)cur[p][2], ya.z, s);
            s = fmaf((float)cur[p][3], ya.w, s);
            s = fmaf((float)cur[p][4], yb.x, s);
            s = fmaf((float)cur[p][5], yb.y, s);
            s = fmaf((float)cur[p][6], yb.z, s);
            s = fmaf((float)cur[p][7], yb.w, s);
        }
#pragma unroll
        for (int o = 1; o < 64; o <<= 1) s += __shfl_xor(s, o, 64);
        // x-update (all lanes compute; lane 0 writes)
        float xo = x[j];
        float xn = xo - tau * (c[j] + s);
        xn = fminf(fmaxf(xn, 0.f), b[j]);
        if (lane == 0) x[j] = xn;
        float z = 2.f * xn - xo;
        // rank-1: acc += z * AT_j (register reuse)
#pragma unroll
        for (int p = 0; p < 8; ++p) {
#pragma unroll
            for (int e = 0; e < 8; ++e)
                acc[p * 8 + e] = fmaf((float)cur[p][e], z, acc[p * 8 + e]);
        }
#pragma unroll
        for (int p = 0; p < 8; ++p) cur[p] = nxt[p];
    }
    // merge 4 waves into ypart (deterministic, conflict-free)
    for (int w = 0; w < 4; ++w) {
        if (wv == w) {
#pragma unroll
            for (int p = 0; p < 8; ++p) {
                float4* pa = reinterpret_cast<float4*>(&ypart[p * 512 + lane * 4]);
                float4* pb = reinterpret_cast<float4*>(&ypart[p * 512 + 256 + lane * 4]);
                float4 va = make_float4(acc[p * 8 + 0], acc[p * 8 + 1], acc[p * 8 + 2], acc[p * 8 + 3]);
                float4 vb = make_float4(acc[p * 8 + 4], acc[p * 8 + 5], acc[p * 8 + 6], acc[p * 8 + 7]);
                if (w == 0) { *pa = va; *pb = vb; }
                else {
                    float4 oa = *pa, ob = *pb;
                    oa.x += va.x; oa.y += va.y; oa.z += va.z; oa.w += va.w;
                    ob.x += vb.x; ob.y += vb.y; ob.z += vb.z; ob.w += vb.w;
                    *pa = oa; *pb = ob;
                }
            }
        }
        __syncthreads();
    }
    float4* __restrict__ P4 = reinterpret_cast<float4*>(partial + (size_t)blockIdx.x * 4096);
    const float4* __restrict__ S4 = reinterpret_cast<const float4*>(ypart);
#pragma unroll
    for (int k = 0; k < 4; ++k) P4[k * 256 + tid] = S4[k * 256 + tid];
}

// ---------------- y update: MODE 0: out = sum ; MODE 1: out += sigma * sum ----------------
template <int MODE, int NP>
__global__ __launch_bounds__(256) void k_y_update(const float* __restrict__ partial,
                                                  float* __restrict__ out,
                                                  const float* __restrict__ scalars) {
    int i = blockIdx.x * 256 + threadIdx.x;     // 0..4095
    float s = 0.f;
    for (int p = 0; p < NP; ++p) s += partial[(size_t)p * NPAD + i];
    if (MODE == 0) out[i] = s;
    else           out[i] += scalars[1] * s;
}

// ---------------- power iter: w[j] = <AT_j, u> (permuted layout, u global) ----------------
__global__ __launch_bounds__(256) void k_colp(const half_t* __restrict__ AT,
                                              const float* __restrict__ u,
                                              float* __restrict__ w) {
    const int wv = threadIdx.x >> 6, lane = threadIdx.x & 63;
    const int j = blockIdx.x * 4 + wv;
    const half8* __restrict__ A8 = reinterpret_cast<const half8*>(AT);
    const float4* __restrict__ u4 = reinterpret_cast<const float4*>(u);
    float s = 0.f;
#pragma unroll
    for (int p = 0; p < 8; ++p) {
        half8 a = A8[(size_t)j * 512 + p * 64 + lane];
        float4 ua = u4[p * 128 + lane];
        float4 ub = u4[p * 128 + 64 + lane];
        s = fmaf((float)a[0], ua.x, s);
        s = fmaf((float)a[1], ua.y, s);
        s = fmaf((float)a[2], ua.z, s);
        s = fmaf((float)a[3], ua.w, s);
        s = fmaf((float)a[4], ub.x, s);
        s = fmaf((float)a[5], ub.y, s);
        s = fmaf((float)a[6], ub.z, s);
        s = fmaf((float)a[7], ub.w, s);
    }
#pragma unroll
    for (int o = 1; o < 64; o <<= 1) s += __shfl_xor(s, o, 64);
    if (lane == 0) w[j] = s;
}

// ---------------- power iter: partial[ch][i] = sum_{j in ch} AT[j][i]*v[j] (permuted) ----
__global__ __launch_bounds__(256) void k_azp(const half_t* __restrict__ AT,
                                             const float* __restrict__ zv,
                                             float* __restrict__ partial) {
    const int ch = blockIdx.y;
    const int j0 = ch * AZ_J;
    const int p = blockIdx.x * 256 + threadIdx.x;   // phys half8 idx 0..511
    __shared__ float sz[AZ_J];
    if (threadIdx.x < AZ_J) sz[threadIdx.x] = zv[j0 + threadIdx.x];
    __syncthreads();
    const half8* __restrict__ A8 = reinterpret_cast<const half8*>(AT);
    float acc[8];
#pragma unroll
    for (int e = 0; e < 8; ++e) acc[e] = 0.f;
    for (int jj = 0; jj < AZ_J; ++jj) {
        half8 a = A8[(size_t)(j0 + jj) * 512 + p];
        float zj = sz[jj];
#pragma unroll
        for (int e = 0; e < 8; ++e) acc[e] = fmaf((float)a[e], zj, acc[e]);
    }
    const int ibase = (p >> 6) * 512 + (p & 63) * 4;
    float* __restrict__ P = partial + (size_t)ch * NPAD;
    *reinterpret_cast<float4*>(&P[ibase])       = make_float4(acc[0], acc[1], acc[2], acc[3]);
    *reinterpret_cast<float4*>(&P[ibase + 256]) = make_float4(acc[4], acc[5], acc[6], acc[7]);
}

// ================= fp32 fallback kernels (round-1 verified) =================
__global__ __launch_bounds__(256) void k_at_partial(const float* __restrict__ A,
                                                    const float* __restrict__ u,
                                                    float* __restrict__ partial) {
    const int j4 = blockIdx.x * 256 + threadIdx.x;
    const int r0 = blockIdx.y * ROWS_PER_CHUNK;
    const int r1 = min(r0 + ROWS_PER_CHUNK, N_ROWS);
    __shared__ float su[ROWS_PER_CHUNK];
    if (threadIdx.x < (unsigned)(r1 - r0)) su[threadIdx.x] = u[r0 + threadIdx.x];
    __syncthreads();
    const float4* __restrict__ A4 = reinterpret_cast<const float4*>(A);
    float4 acc = make_float4(0.f, 0.f, 0.f, 0.f);
    for (int i = r0; i < r1; ++i) {
        const float ui = su[i - r0];
        float4 a = A4[(size_t)i * M4 + j4];
        acc.x = fmaf(a.x, ui, acc.x);
        acc.y = fmaf(a.y, ui, acc.y);
        acc.z = fmaf(a.z, ui, acc.z);
        acc.w = fmaf(a.w, ui, acc.w);
    }
    reinterpret_cast<float4*>(partial)[(size_t)blockIdx.y * M4 + j4] = acc;
}

__global__ __launch_bounds__(256) void k_reduce_w(const float* __restrict__ partial,
                                                  float* __restrict__ w) {
    int j = blockIdx.x * 256 + threadIdx.x;
    float s = 0.f;
    for (int p = 0; p < P_CHUNKS; ++p) s += partial[(size_t)p * M_COLS + j];
    w[j] = s;
}

__global__ __launch_bounds__(256) void k_x_update(const float* __restrict__ partial,
                                                  const float* __restrict__ c,
                                                  const float* __restrict__ b,
                                                  float* __restrict__ x,
                                                  float* __restrict__ z,
                                                  const float* __restrict__ scalars) {
    int j = blockIdx.x * 256 + threadIdx.x;
    const float tau = scalars[1];
    float s = 0.f;
    for (int p = 0; p < P_CHUNKS; ++p) s += partial[(size_t)p * M_COLS + j];
    float xo = x[j];
    float xn = xo - tau * (c[j] + s);
    xn = fminf(fmaxf(xn, 0.f), b[j]);
    x[j] = xn;
    z[j] = 2.f * xn - xo;
}

template <int MODE>
__global__ __launch_bounds__(256) void k_row_dot(const float* __restrict__ A,
                                                 const float* __restrict__ vec,
                                                 float* __restrict__ out,
                                                 const float* __restrict__ scalars) {
    const int i = blockIdx.x;
    const float4* __restrict__ row = reinterpret_cast<const float4*>(A + (size_t)i * M_COLS);
    const float4* __restrict__ v4  = reinterpret_cast<const float4*>(vec);
    float s = 0.f;
    for (int k = threadIdx.x; k < M4; k += 256) {
        float4 a = row[k];
        float4 v = v4[k];
        s = fmaf(a.x, v.x, s);
        s = fmaf(a.y, v.y, s);
        s = fmaf(a.z, v.z, s);
        s = fmaf(a.w, v.w, s);
    }
    for (int o = 32; o > 0; o >>= 1) s += __shfl_down(s, o, 64);
    __shared__ float sm[4];
    if ((threadIdx.x & 63) == 0) sm[threadIdx.x >> 6] = s;
    __syncthreads();
    if (threadIdx.x == 0) {
        float t = sm[0] + sm[1] + sm[2] + sm[3];
        if (MODE == 0) out[i] = t;
        else           out[i] += scalars[1] * t;
    }
}

// ---------------- shared small kernels ----------------
template <int MODE>
__global__ __launch_bounds__(1024) void k_norm(const float* __restrict__ w,
                                               float* __restrict__ scalars) {
    const float4* __restrict__ w4 = reinterpret_cast<const float4*>(w);
    float s = 0.f;
    for (int k = threadIdx.x; k < M4; k += 1024) {
        float4 a = w4[k];
        s = fmaf(a.x, a.x, s);
        s = fmaf(a.y, a.y, s);
        s = fmaf(a.z, a.z, s);
        s = fmaf(a.w, a.w, s);
    }
    for (int o = 32; o > 0; o >>= 1) s += __shfl_down(s, o, 64);
    __shared__ float sm[16];
    if ((threadIdx.x & 63) == 0) sm[threadIdx.x >> 6] = s;
    __syncthreads();
    if (threadIdx.x == 0) {
        float t = 0.f;
        for (int q = 0; q < 16; ++q) t += sm[q];
        float nrm = sqrtf(t);
        if (MODE == 0) scalars[0] = nrm;
        else           scalars[1] = 0.9f / sqrtf(nrm);
    }
}

__global__ __launch_bounds__(256) void k_scale(const float* __restrict__ w,
                                               float* __restrict__ v,
                                               const float* __restrict__ scalars) {
    int j = blockIdx.x * 256 + threadIdx.x;
    v[j] = w[j] / scalars[0];
}

__global__ __launch_bounds__(1024) void k_obj(const float* __restrict__ x,
                                              const float* __restrict__ c,
                                              float* __restrict__ out) {
    float s = 0.f;
    for (int k = threadIdx.x; k < M_COLS; k += 1024) s = fmaf(x[k], -c[k], s);
    for (int o = 32; o > 0; o >>= 1) s += __shfl_down(s, o, 64);
    __shared__ float sm[16];
    if ((threadIdx.x & 63) == 0) sm[threadIdx.x >> 6] = s;
    __syncthreads();
    if (threadIdx.x == 0) {
        float t = 0.f;
        for (int q = 0; q < 16; ++q) t += sm[q];
        out[0] = t;
    }
}

extern "C" void kernel_launch(void* const* d_in, const int* in_sizes, int n_in,
                              void* d_out, int out_size, void* d_ws, size_t ws_size,
                              hipStream_t stream) {
    const float* A = (const float*)d_in[0];
    const float* b = (const float*)d_in[1];
    const float* c = (const float*)d_in[2];
    float* out = (float*)d_out;

    float* ws = (float*)d_ws;
    float* x       = ws;                        // M
    float* z       = x + M_COLS;                // M (fallback only)
    float* v       = z + M_COLS;                // M
    float* w       = v + M_COLS;                // M
    float* y       = w + M_COLS;                // NPAD
    float* t       = y + NPAD;                  // NPAD
    float* scalars = t + NPAD;                  // 16
    float* partial = scalars + 16;              // 8 MB region

    size_t partial_floats = (size_t)2 * 1024 * 1024;  // max(512*4096, 64*16384)
    size_t base = (size_t)(partial - ws) * 4 + partial_floats * 4;
    size_t at_off = (base + 255) & ~(size_t)255;
    half_t* AT16 = (half_t*)((char*)d_ws + at_off);
    size_t at_bytes = (size_t)M_COLS * NPAD * sizeof(half_t);  // 134.2 MB
    size_t need_at   = at_off + at_bytes;                      // ~143 MB
    size_t need_fp32 = (size_t)(partial - ws) * 4 + (size_t)P_CHUNKS * M_COLS * 4;

    dim3 b256(256);
    dim3 gM(M_COLS / 256);            // 64
    dim3 gCol(M_COLS / 4);            // 4096
    dim3 gFused(FBLOCKS);             // 512
    dim3 gAz(NPAD / 8 / 256, AZ_CH);  // (2, 256)
    dim3 gYU(NPAD / 256);             // 16
    dim3 gRowA(N_ROWS);
    dim3 gTr(NPAD / 64, M_COLS / 64); // (64, 256)

    k_init<<<gM, b256, 0, stream>>>(x, v, y, t);

    if (ws_size >= need_at) {
        // ======== permuted-AT fused path ========
        k_transpose<<<gTr, b256, 0, stream>>>(A, AT16);

        for (int it = 0; it < POWER_ITERS; ++it) {
            k_azp<<<gAz, b256, 0, stream>>>(AT16, v, partial);             // A v chunks
            k_y_update<0, AZ_CH><<<gYU, b256, 0, stream>>>(partial, t, scalars); // t = A v
            k_colp<<<gCol, b256, 0, stream>>>(AT16, t, w);                 // w = A^T t
            k_norm<0><<<1, 1024, 0, stream>>>(w, scalars);
            k_scale<<<gM, b256, 0, stream>>>(w, v, scalars);
        }
        k_azp<<<gAz, b256, 0, stream>>>(AT16, v, partial);
        k_y_update<0, AZ_CH><<<gYU, b256, 0, stream>>>(partial, t, scalars);
        k_colp<<<gCol, b256, 0, stream>>>(AT16, t, w);
        k_norm<1><<<1, 1024, 0, stream>>>(w, scalars);                     // tau = sigma

        for (int it = 0; it < PDHG_ITERS; ++it) {
            k_fused<<<gFused, b256, 0, stream>>>(AT16, y, c, b, x, partial, scalars);
            k_y_update<1, FBLOCKS><<<gYU, b256, 0, stream>>>(partial, y, scalars);
        }
    } else if (ws_size >= need_fp32) {
        // ======== fp32 fallback ========
        dim3 gAt(M4 / 256, P_CHUNKS);
        for (int it = 0; it < POWER_ITERS; ++it) {
            k_row_dot<0><<<gRowA, b256, 0, stream>>>(A, v, t, scalars);
            k_at_partial<<<gAt, b256, 0, stream>>>(A, t, partial);
            k_reduce_w<<<gM, b256, 0, stream>>>(partial, w);
            k_norm<0><<<1, 1024, 0, stream>>>(w, scalars);
            k_scale<<<gM, b256, 0, stream>>>(w, v, scalars);
        }
        k_row_dot<0><<<gRowA, b256, 0, stream>>>(A, v, t, scalars);
        k_at_partial<<<gAt, b256, 0, stream>>>(A, t, partial);
        k_reduce_w<<<gM, b256, 0, stream>>>(partial, w);
        k_norm<1><<<1, 1024, 0, stream>>>(w, scalars);
        for (int it = 0; it < PDHG_ITERS; ++it) {
            k_at_partial<<<gAt, b256, 0, stream>>>(A, y, partial);
            k_x_update<<<gM, b256, 0, stream>>>(partial, c, b, x, z, scalars);
            k_row_dot<1><<<gRowA, b256, 0, stream>>>(A, z, y, scalars);
        }
    }

    k_obj<<<1, 1024, 0, stream>>>(x, c, out);
}

// Round 6
// 10409.752 us; speedup vs baseline: 1.6756x; 1.4391x over previous
//
#include <hip/hip_runtime.h>

// LP via PDHG. A: (4094, 16384) row-major fp32; b, c: (16384,) fp32. Out: scalar fp32.
// Round 6: fused single-pass PDHG (134 MB/iter) +
//   (a) parallel partial-merge kernel (k_merge: 256 blocks, coalesced) replacing
//       the 16-block latency-bound reduce (~13us -> ~3us per iter)
//   (b) x/c/b hoisted into lane registers in k_fused (removes per-column ~300cy
//       serial L2 stalls from the dot->reduce->update->rank1 chain)
// Permuted AT layout (per column j, 512 half8s): half8 p (it=p>>6, l=p&63) holds
// slots i = it*512 + sub*256 + l*4 + e (sub=e>>2 of half4 pair) -> conflict-free
// LDS + coalesced global. fp32 fallback kept.

constexpr int N_ROWS = 4094;
constexpr int NPAD   = 4096;
constexpr int M_COLS = 16384;
constexpr int M4     = M_COLS / 4;
constexpr int PDHG_ITERS  = 300;
constexpr int POWER_ITERS = 20;
constexpr int P_CHUNKS = 64;        // fp32 fallback
constexpr int ROWS_PER_CHUNK = 64;  // fp32 fallback
constexpr int FJ = 32;              // columns per fused block
constexpr int FBLOCKS = M_COLS / FJ;       // 512
constexpr int AZ_J  = 64;
constexpr int AZ_CH = M_COLS / AZ_J;       // 256

typedef _Float16 half8 __attribute__((ext_vector_type(8)));
typedef _Float16 half4 __attribute__((ext_vector_type(4)));
typedef _Float16 half_t;

// ---------------- init ----------------
__global__ __launch_bounds__(256) void k_init(float* __restrict__ x,
                                              float* __restrict__ v,
                                              float* __restrict__ y,
                                              float* __restrict__ t) {
    int j = blockIdx.x * 256 + threadIdx.x;
    if (j < M_COLS) { x[j] = 0.f; v[j] = 0.0078125f; }
    if (j < NPAD) { y[j] = 0.f; t[j] = 0.f; }
}

// ---------------- A -> permuted fp16 AT ----------------
__global__ __launch_bounds__(256) void k_transpose(const float* __restrict__ A,
                                                   half_t* __restrict__ AT) {
    __shared__ float tile[64][65];
    const int i0 = blockIdx.x * 64;   // row tile base
    const int j0 = blockIdx.y * 64;   // col tile base
    const int t = threadIdx.x;
    const float4* __restrict__ A4 = reinterpret_cast<const float4*>(A);
#pragma unroll
    for (int k = 0; k < 4; ++k) {
        int idx = k * 256 + t;        // 0..1023
        int r = idx >> 4, c4 = idx & 15;
        int i = i0 + r;
        float4 val = (i < N_ROWS) ? A4[(size_t)i * M4 + (j0 >> 2) + c4]
                                  : make_float4(0.f, 0.f, 0.f, 0.f);
        tile[r][c4 * 4 + 0] = val.x;
        tile[r][c4 * 4 + 1] = val.y;
        tile[r][c4 * 4 + 2] = val.z;
        tile[r][c4 * 4 + 3] = val.w;
    }
    __syncthreads();
    const int it_p = i0 >> 9;
    const int sub  = (i0 >> 8) & 1;
    const int l0   = (i0 & 255) >> 2;   // {0,16,32,48}
    half4* __restrict__ O4 = reinterpret_cast<half4*>(AT);
#pragma unroll
    for (int k = 0; k < 4; ++k) {
        int idx = k * 256 + t;        // 0..1023 = 64 j x 16 lofs
        int j = idx >> 4, lofs = idx & 15;
        half4 h;
#pragma unroll
        for (int e = 0; e < 4; ++e) h[e] = (half_t)tile[lofs * 4 + e][j];
        O4[(size_t)(j0 + j) * 1024 + it_p * 128 + (l0 + lofs) * 2 + sub] = h;
    }
}

// ---------------- fused PDHG x-pass + rank-1 accumulate ----------------
__global__ __launch_bounds__(256) void k_fused(const half_t* __restrict__ AT,
                                               const float* __restrict__ y,
                                               const float* __restrict__ c,
                                               const float* __restrict__ b,
                                               float* __restrict__ x,
                                               float* __restrict__ partial,
                                               const float* __restrict__ scalars) {
    __shared__ float yIn[4096];
    __shared__ float ypart[4096];
    const int tid = threadIdx.x;
    const int wv = tid >> 6, lane = tid & 63;
    {
        const float4* __restrict__ y4 = reinterpret_cast<const float4*>(y);
        float4* s4 = reinterpret_cast<float4*>(yIn);
#pragma unroll
        for (int k = 0; k < 4; ++k) s4[k * 256 + tid] = y4[k * 256 + tid];
    }
    __syncthreads();
    const float tau = scalars[1];
    const int j0 = blockIdx.x * FJ + wv * (FJ / 4);  // 8 cols per wave
    const half8* __restrict__ A8 = reinterpret_cast<const half8*>(AT);

    // hoist x/c/b for the wave's 8 columns into lane registers
    float xs = 0.f, cs = 0.f, bs = 0.f, xkeep = 0.f;
    if (lane < 8) {
        xs = x[j0 + lane];
        cs = c[j0 + lane];
        bs = b[j0 + lane];
    }

    float acc[64];
#pragma unroll
    for (int q = 0; q < 64; ++q) acc[q] = 0.f;

    half8 cur[8], nxt[8];
#pragma unroll
    for (int p = 0; p < 8; ++p) cur[p] = A8[(size_t)j0 * 512 + p * 64 + lane];

    for (int q = 0; q < FJ / 4; ++q) {
        const int j = j0 + q;
        if (q + 1 < FJ / 4) {
#pragma unroll
            for (int p = 0; p < 8; ++p) nxt[p] = A8[(size_t)(j + 1) * 512 + p * 64 + lane];
        }
        float s = 0.f;
#pragma unroll
        for (int p = 0; p < 8; ++p) {
            const float4 ya = *reinterpret_cast<const float4*>(&yIn[p * 512 + lane * 4]);
            const float4 yb = *reinterpret_cast<const float4*>(&yIn[p * 512 + 256 + lane * 4]);
            s = fmaf((float)cur[p][0], ya.x, s);
            s = fmaf((float)cur[p][1], ya.y, s);
            s = fmaf((float)cur[p][2], ya.z, s);
            s = fmaf((float)cur[p][3], ya.w, s);
            s = fmaf((float)cur[p][4], yb.x, s);
            s = fmaf((float)cur[p][5], yb.y, s);
            s = fmaf((float)cur[p][6], yb.z, s);
            s = fmaf((float)cur[p][7], yb.w, s);
        }
#pragma unroll
        for (int o = 1; o < 64; o <<= 1) s += __shfl_xor(s, o, 64);
        // x-update from hoisted registers (all lanes compute)
        float xo = __shfl(xs, q, 64);
        float cj = __shfl(cs, q, 64);
        float bj = __shfl(bs, q, 64);
        float xn = xo - tau * (cj + s);
        xn = fminf(fmaxf(xn, 0.f), bj);
        if (lane == q) xkeep = xn;
        float z = 2.f * xn - xo;
        // rank-1: acc += z * AT_j (register reuse)
#pragma unroll
        for (int p = 0; p < 8; ++p) {
#pragma unroll
            for (int e = 0; e < 8; ++e)
                acc[p * 8 + e] = fmaf((float)cur[p][e], z, acc[p * 8 + e]);
        }
#pragma unroll
        for (int p = 0; p < 8; ++p) cur[p] = nxt[p];
    }
    if (lane < 8) x[j0 + lane] = xkeep;

    // merge 4 waves into ypart (deterministic, conflict-free)
    for (int w = 0; w < 4; ++w) {
        if (wv == w) {
#pragma unroll
            for (int p = 0; p < 8; ++p) {
                float4* pa = reinterpret_cast<float4*>(&ypart[p * 512 + lane * 4]);
                float4* pb = reinterpret_cast<float4*>(&ypart[p * 512 + 256 + lane * 4]);
                float4 va = make_float4(acc[p * 8 + 0], acc[p * 8 + 1], acc[p * 8 + 2], acc[p * 8 + 3]);
                float4 vb = make_float4(acc[p * 8 + 4], acc[p * 8 + 5], acc[p * 8 + 6], acc[p * 8 + 7]);
                if (w == 0) { *pa = va; *pb = vb; }
                else {
                    float4 oa = *pa, ob = *pb;
                    oa.x += va.x; oa.y += va.y; oa.z += va.z; oa.w += va.w;
                    ob.x += vb.x; ob.y += vb.y; ob.z += vb.z; ob.w += vb.w;
                    *pa = oa; *pb = ob;
                }
            }
        }
        __syncthreads();
    }
    float4* __restrict__ P4 = reinterpret_cast<float4*>(partial + (size_t)blockIdx.x * 4096);
    const float4* __restrict__ S4 = reinterpret_cast<const float4*>(ypart);
#pragma unroll
    for (int k = 0; k < 4; ++k) P4[k * 256 + tid] = S4[k * 256 + tid];
}

// ---------------- parallel partial merge: 256 blocks, 16 rows x 16 groups ----------------
// MODE 0: out[row] = sum_p partial[p][row] ; MODE 1: out[row] += sigma * sum
template <int MODE, int NP>
__global__ __launch_bounds__(256) void k_merge(const float* __restrict__ partial,
                                               float* __restrict__ out,
                                               const float* __restrict__ scalars) {
    constexpr int PER = NP / 16;
    const int tid = threadIdx.x;
    const int r = tid & 15, k = tid >> 4;        // 16 rows x 16 partial-groups
    const int row = blockIdx.x * 16 + r;
    const float* __restrict__ p0 = partial + (size_t)k * PER * NPAD + row;
    float s = 0.f;
#pragma unroll 8
    for (int q = 0; q < PER; ++q) s += p0[(size_t)q * NPAD];
    __shared__ float sm[256];
    sm[tid] = s;
    __syncthreads();
    if (tid < 16) {
        const int orow = blockIdx.x * 16 + tid;
        float tot = 0.f;
#pragma unroll
        for (int kk = 0; kk < 16; ++kk) tot += sm[kk * 16 + tid];
        if (MODE == 0) out[orow] = tot;
        else           out[orow] += scalars[1] * tot;
    }
}

// ---------------- power iter: w[j] = <AT_j, u> (permuted layout) ----------------
__global__ __launch_bounds__(256) void k_colp(const half_t* __restrict__ AT,
                                              const float* __restrict__ u,
                                              float* __restrict__ w) {
    const int wv = threadIdx.x >> 6, lane = threadIdx.x & 63;
    const int j = blockIdx.x * 4 + wv;
    const half8* __restrict__ A8 = reinterpret_cast<const half8*>(AT);
    const float4* __restrict__ u4 = reinterpret_cast<const float4*>(u);
    float s = 0.f;
#pragma unroll
    for (int p = 0; p < 8; ++p) {
        half8 a = A8[(size_t)j * 512 + p * 64 + lane];
        float4 ua = u4[p * 128 + lane];
        float4 ub = u4[p * 128 + 64 + lane];
        s = fmaf((float)a[0], ua.x, s);
        s = fmaf((float)a[1], ua.y, s);
        s = fmaf((float)a[2], ua.z, s);
        s = fmaf((float)a[3], ua.w, s);
        s = fmaf((float)a[4], ub.x, s);
        s = fmaf((float)a[5], ub.y, s);
        s = fmaf((float)a[6], ub.z, s);
        s = fmaf((float)a[7], ub.w, s);
    }
#pragma unroll
    for (int o = 1; o < 64; o <<= 1) s += __shfl_xor(s, o, 64);
    if (lane == 0) w[j] = s;
}

// ---------------- power iter: partial[ch][i] = sum_{j in ch} AT[j][i]*v[j] (permuted) ----
__global__ __launch_bounds__(256) void k_azp(const half_t* __restrict__ AT,
                                             const float* __restrict__ zv,
                                             float* __restrict__ partial) {
    const int ch = blockIdx.y;
    const int j0 = ch * AZ_J;
    const int p = blockIdx.x * 256 + threadIdx.x;   // phys half8 idx 0..511
    __shared__ float sz[AZ_J];
    if (threadIdx.x < AZ_J) sz[threadIdx.x] = zv[j0 + threadIdx.x];
    __syncthreads();
    const half8* __restrict__ A8 = reinterpret_cast<const half8*>(AT);
    float acc[8];
#pragma unroll
    for (int e = 0; e < 8; ++e) acc[e] = 0.f;
    for (int jj = 0; jj < AZ_J; ++jj) {
        half8 a = A8[(size_t)(j0 + jj) * 512 + p];
        float zj = sz[jj];
#pragma unroll
        for (int e = 0; e < 8; ++e) acc[e] = fmaf((float)a[e], zj, acc[e]);
    }
    const int ibase = (p >> 6) * 512 + (p & 63) * 4;
    float* __restrict__ P = partial + (size_t)ch * NPAD;
    *reinterpret_cast<float4*>(&P[ibase])       = make_float4(acc[0], acc[1], acc[2], acc[3]);
    *reinterpret_cast<float4*>(&P[ibase + 256]) = make_float4(acc[4], acc[5], acc[6], acc[7]);
}

// ================= fp32 fallback kernels (round-1 verified) =================
__global__ __launch_bounds__(256) void k_at_partial(const float* __restrict__ A,
                                                    const float* __restrict__ u,
                                                    float* __restrict__ partial) {
    const int j4 = blockIdx.x * 256 + threadIdx.x;
    const int r0 = blockIdx.y * ROWS_PER_CHUNK;
    const int r1 = min(r0 + ROWS_PER_CHUNK, N_ROWS);
    __shared__ float su[ROWS_PER_CHUNK];
    if (threadIdx.x < (unsigned)(r1 - r0)) su[threadIdx.x] = u[r0 + threadIdx.x];
    __syncthreads();
    const float4* __restrict__ A4 = reinterpret_cast<const float4*>(A);
    float4 acc = make_float4(0.f, 0.f, 0.f, 0.f);
    for (int i = r0; i < r1; ++i) {
        const float ui = su[i - r0];
        float4 a = A4[(size_t)i * M4 + j4];
        acc.x = fmaf(a.x, ui, acc.x);
        acc.y = fmaf(a.y, ui, acc.y);
        acc.z = fmaf(a.z, ui, acc.z);
        acc.w = fmaf(a.w, ui, acc.w);
    }
    reinterpret_cast<float4*>(partial)[(size_t)blockIdx.y * M4 + j4] = acc;
}

__global__ __launch_bounds__(256) void k_reduce_w(const float* __restrict__ partial,
                                                  float* __restrict__ w) {
    int j = blockIdx.x * 256 + threadIdx.x;
    float s = 0.f;
    for (int p = 0; p < P_CHUNKS; ++p) s += partial[(size_t)p * M_COLS + j];
    w[j] = s;
}

__global__ __launch_bounds__(256) void k_x_update(const float* __restrict__ partial,
                                                  const float* __restrict__ c,
                                                  const float* __restrict__ b,
                                                  float* __restrict__ x,
                                                  float* __restrict__ z,
                                                  const float* __restrict__ scalars) {
    int j = blockIdx.x * 256 + threadIdx.x;
    const float tau = scalars[1];
    float s = 0.f;
    for (int p = 0; p < P_CHUNKS; ++p) s += partial[(size_t)p * M_COLS + j];
    float xo = x[j];
    float xn = xo - tau * (c[j] + s);
    xn = fminf(fmaxf(xn, 0.f), b[j]);
    x[j] = xn;
    z[j] = 2.f * xn - xo;
}

template <int MODE>
__global__ __launch_bounds__(256) void k_row_dot(const float* __restrict__ A,
                                                 const float* __restrict__ vec,
                                                 float* __restrict__ out,
                                                 const float* __restrict__ scalars) {
    const int i = blockIdx.x;
    const float4* __restrict__ row = reinterpret_cast<const float4*>(A + (size_t)i * M_COLS);
    const float4* __restrict__ v4  = reinterpret_cast<const float4*>(vec);
    float s = 0.f;
    for (int k = threadIdx.x; k < M4; k += 256) {
        float4 a = row[k];
        float4 v = v4[k];
        s = fmaf(a.x, v.x, s);
        s = fmaf(a.y, v.y, s);
        s = fmaf(a.z, v.z, s);
        s = fmaf(a.w, v.w, s);
    }
    for (int o = 32; o > 0; o >>= 1) s += __shfl_down(s, o, 64);
    __shared__ float sm[4];
    if ((threadIdx.x & 63) == 0) sm[threadIdx.x >> 6] = s;
    __syncthreads();
    if (threadIdx.x == 0) {
        float t = sm[0] + sm[1] + sm[2] + sm[3];
        if (MODE == 0) out[i] = t;
        else           out[i] += scalars[1] * t;
    }
}

// ---------------- shared small kernels ----------------
template <int MODE>
__global__ __launch_bounds__(1024) void k_norm(const float* __restrict__ w,
                                               float* __restrict__ scalars) {
    const float4* __restrict__ w4 = reinterpret_cast<const float4*>(w);
    float s = 0.f;
    for (int k = threadIdx.x; k < M4; k += 1024) {
        float4 a = w4[k];
        s = fmaf(a.x, a.x, s);
        s = fmaf(a.y, a.y, s);
        s = fmaf(a.z, a.z, s);
        s = fmaf(a.w, a.w, s);
    }
    for (int o = 32; o > 0; o >>= 1) s += __shfl_down(s, o, 64);
    __shared__ float sm[16];
    if ((threadIdx.x & 63) == 0) sm[threadIdx.x >> 6] = s;
    __syncthreads();
    if (threadIdx.x == 0) {
        float t = 0.f;
        for (int q = 0; q < 16; ++q) t += sm[q];
        float nrm = sqrtf(t);
        if (MODE == 0) scalars[0] = nrm;
        else           scalars[1] = 0.9f / sqrtf(nrm);
    }
}

__global__ __launch_bounds__(256) void k_scale(const float* __restrict__ w,
                                               float* __restrict__ v,
                                               const float* __restrict__ scalars) {
    int j = blockIdx.x * 256 + threadIdx.x;
    v[j] = w[j] / scalars[0];
}

__global__ __launch_bounds__(1024) void k_obj(const float* __restrict__ x,
                                              const float* __restrict__ c,
                                              float* __restrict__ out) {
    float s = 0.f;
    for (int k = threadIdx.x; k < M_COLS; k += 1024) s = fmaf(x[k], -c[k], s);
    for (int o = 32; o > 0; o >>= 1) s += __shfl_down(s, o, 64);
    __shared__ float sm[16];
    if ((threadIdx.x & 63) == 0) sm[threadIdx.x >> 6] = s;
    __syncthreads();
    if (threadIdx.x == 0) {
        float t = 0.f;
        for (int q = 0; q < 16; ++q) t += sm[q];
        out[0] = t;
    }
}

extern "C" void kernel_launch(void* const* d_in, const int* in_sizes, int n_in,
                              void* d_out, int out_size, void* d_ws, size_t ws_size,
                              hipStream_t stream) {
    const float* A = (const float*)d_in[0];
    const float* b = (const float*)d_in[1];
    const float* c = (const float*)d_in[2];
    float* out = (float*)d_out;

    float* ws = (float*)d_ws;
    float* x       = ws;                        // M
    float* z       = x + M_COLS;                // M (fallback only)
    float* v       = z + M_COLS;                // M
    float* w       = v + M_COLS;                // M
    float* y       = w + M_COLS;                // NPAD
    float* t       = y + NPAD;                  // NPAD
    float* scalars = t + NPAD;                  // 16
    float* partial = scalars + 16;              // 8 MB region

    size_t partial_floats = (size_t)2 * 1024 * 1024;  // max(512*4096, 64*16384)
    size_t base = (size_t)(partial - ws) * 4 + partial_floats * 4;
    size_t at_off = (base + 255) & ~(size_t)255;
    half_t* AT16 = (half_t*)((char*)d_ws + at_off);
    size_t at_bytes = (size_t)M_COLS * NPAD * sizeof(half_t);  // 134.2 MB
    size_t need_at   = at_off + at_bytes;                      // ~143 MB
    size_t need_fp32 = (size_t)(partial - ws) * 4 + (size_t)P_CHUNKS * M_COLS * 4;

    dim3 b256(256);
    dim3 gM(M_COLS / 256);            // 64
    dim3 gCol(M_COLS / 4);            // 4096
    dim3 gFused(FBLOCKS);             // 512
    dim3 gAz(NPAD / 8 / 256, AZ_CH);  // (2, 256)
    dim3 gMerge(NPAD / 16);           // 256
    dim3 gRowA(N_ROWS);
    dim3 gTr(NPAD / 64, M_COLS / 64); // (64, 256)

    k_init<<<gM, b256, 0, stream>>>(x, v, y, t);

    if (ws_size >= need_at) {
        // ======== permuted-AT fused path ========
        k_transpose<<<gTr, b256, 0, stream>>>(A, AT16);

        for (int it = 0; it < POWER_ITERS; ++it) {
            k_azp<<<gAz, b256, 0, stream>>>(AT16, v, partial);               // A v chunks
            k_merge<0, AZ_CH><<<gMerge, b256, 0, stream>>>(partial, t, scalars); // t = A v
            k_colp<<<gCol, b256, 0, stream>>>(AT16, t, w);                   // w = A^T t
            k_norm<0><<<1, 1024, 0, stream>>>(w, scalars);
            k_scale<<<gM, b256, 0, stream>>>(w, v, scalars);
        }
        k_azp<<<gAz, b256, 0, stream>>>(AT16, v, partial);
        k_merge<0, AZ_CH><<<gMerge, b256, 0, stream>>>(partial, t, scalars);
        k_colp<<<gCol, b256, 0, stream>>>(AT16, t, w);
        k_norm<1><<<1, 1024, 0, stream>>>(w, scalars);                       // tau = sigma

        for (int it = 0; it < PDHG_ITERS; ++it) {
            k_fused<<<gFused, b256, 0, stream>>>(AT16, y, c, b, x, partial, scalars);
            k_merge<1, FBLOCKS><<<gMerge, b256, 0, stream>>>(partial, y, scalars);
        }
    } else if (ws_size >= need_fp32) {
        // ======== fp32 fallback ========
        dim3 gAt(M4 / 256, P_CHUNKS);
        for (int it = 0; it < POWER_ITERS; ++it) {
            k_row_dot<0><<<gRowA, b256, 0, stream>>>(A, v, t, scalars);
            k_at_partial<<<gAt, b256, 0, stream>>>(A, t, partial);
            k_reduce_w<<<gM, b256, 0, stream>>>(partial, w);
            k_norm<0><<<1, 1024, 0, stream>>>(w, scalars);
            k_scale<<<gM, b256, 0, stream>>>(w, v, scalars);
        }
        k_row_dot<0><<<gRowA, b256, 0, stream>>>(A, v, t, scalars);
        k_at_partial<<<gAt, b256, 0, stream>>>(A, t, partial);
        k_reduce_w<<<gM, b256, 0, stream>>>(partial, w);
        k_norm<1><<<1, 1024, 0, stream>>>(w, scalars);
        for (int it = 0; it < PDHG_ITERS; ++it) {
            k_at_partial<<<gAt, b256, 0, stream>>>(A, y, partial);
            k_x_update<<<gM, b256, 0, stream>>>(partial, c, b, x, z, scalars);
            k_row_dot<1><<<gRowA, b256, 0, stream>>>(A, z, y, scalars);
        }
    }

    k_obj<<<1, 1024, 0, stream>>>(x, c, out);
}

// Round 7
// 6703.896 us; speedup vs baseline: 2.6018x; 1.5528x over previous
//
#include <hip/hip_runtime.h>

// LP via PDHG. A: (4094, 16384) row-major fp32; b, c: (16384,) fp32. Out: scalar fp32.
// Round 7: fp8-e4m3 matrix (stored as fp8(64*A), permuted layout, 64 MB) for all
// 299 PDHG iterations + power iteration; final x-step (iter 300) polished with a
// true fp16 A^T copy (round-3 k_col). Scale folding:
//   dot_true = dot_raw/64 ; tau = 57.6/sqrt(||w||_meas) (w carries 4096x) ;
//   y-merge uses scalars[2] = tau/64 (partials carry 64x).
// fp32 fallback kept.

constexpr int N_ROWS = 4094;
constexpr int NPAD   = 4096;
constexpr int M_COLS = 16384;
constexpr int M4     = M_COLS / 4;
constexpr int PDHG_ITERS  = 300;
constexpr int POWER_ITERS = 20;
constexpr int P_CHUNKS = 64;        // fp32 fallback
constexpr int ROWS_PER_CHUNK = 64;  // fp32 fallback
constexpr int FJ = 32;              // columns per fused block
constexpr int FBLOCKS = M_COLS / FJ;       // 512
constexpr int AZ_J  = 64;
constexpr int AZ_CH = M_COLS / AZ_J;       // 256

typedef _Float16 half8 __attribute__((ext_vector_type(8)));
typedef _Float16 half_t;
typedef float f32x2 __attribute__((ext_vector_type(2)));

__device__ __forceinline__ void dec8(uint2 w, float* f) {
    f32x2 a = __builtin_amdgcn_cvt_pk_f32_fp8(w.x, false);
    f32x2 b = __builtin_amdgcn_cvt_pk_f32_fp8(w.x, true);
    f32x2 c = __builtin_amdgcn_cvt_pk_f32_fp8(w.y, false);
    f32x2 d = __builtin_amdgcn_cvt_pk_f32_fp8(w.y, true);
    f[0]=a[0]; f[1]=a[1]; f[2]=b[0]; f[3]=b[1];
    f[4]=c[0]; f[5]=c[1]; f[6]=d[0]; f[7]=d[1];
}

// ---------------- init ----------------
__global__ __launch_bounds__(256) void k_init(float* __restrict__ x,
                                              float* __restrict__ v,
                                              float* __restrict__ y,
                                              float* __restrict__ t) {
    int j = blockIdx.x * 256 + threadIdx.x;
    if (j < M_COLS) { x[j] = 0.f; v[j] = 0.0078125f; }
    if (j < NPAD) { y[j] = 0.f; t[j] = 0.f; }
}

// ---------------- A -> permuted fp8 AT8 (values 64*A) ----------------
// per column j (1024 uints): uint u = it*128 + lane*2 + sub holds slots
// i = it*512 + sub*256 + lane*4 + e  (byte e), it<8, lane<64, sub<2.
__global__ __launch_bounds__(256) void k_transpose8(const float* __restrict__ A,
                                                    unsigned int* __restrict__ AT) {
    __shared__ float tile[64][65];
    const int i0 = blockIdx.x * 64;
    const int j0 = blockIdx.y * 64;
    const int t = threadIdx.x;
    const float4* __restrict__ A4 = reinterpret_cast<const float4*>(A);
#pragma unroll
    for (int k = 0; k < 4; ++k) {
        int idx = k * 256 + t;
        int r = idx >> 4, c4 = idx & 15;
        int i = i0 + r;
        float4 val = (i < N_ROWS) ? A4[(size_t)i * M4 + (j0 >> 2) + c4]
                                  : make_float4(0.f, 0.f, 0.f, 0.f);
        tile[r][c4 * 4 + 0] = val.x;
        tile[r][c4 * 4 + 1] = val.y;
        tile[r][c4 * 4 + 2] = val.z;
        tile[r][c4 * 4 + 3] = val.w;
    }
    __syncthreads();
    const int it_p = i0 >> 9;
    const int sub  = (i0 >> 8) & 1;
    const int l0   = (i0 & 255) >> 2;
#pragma unroll
    for (int k = 0; k < 4; ++k) {
        int idx = k * 256 + t;          // 0..1023 = 64 j x 16 lofs
        int j = idx >> 4, lofs = idx & 15;
        float f0 = tile[lofs * 4 + 0][j] * 64.f;
        float f1 = tile[lofs * 4 + 1][j] * 64.f;
        float f2 = tile[lofs * 4 + 2][j] * 64.f;
        float f3 = tile[lofs * 4 + 3][j] * 64.f;
        int r = 0;
        r = __builtin_amdgcn_cvt_pk_fp8_f32(f0, f1, r, false);
        r = __builtin_amdgcn_cvt_pk_fp8_f32(f2, f3, r, true);
        AT[(size_t)(j0 + j) * 1024 + it_p * 128 + (l0 + lofs) * 2 + sub] = (unsigned int)r;
    }
}

// ---------------- A -> linear fp16 AT16 (true values, for final polish) ----------------
__global__ __launch_bounds__(256) void k_transpose16(const float* __restrict__ A,
                                                     half_t* __restrict__ AT) {
    __shared__ float tile[64][65];
    const int i0 = blockIdx.x * 64;
    const int j0 = blockIdx.y * 64;
    const int t = threadIdx.x;
    const float4* __restrict__ A4 = reinterpret_cast<const float4*>(A);
#pragma unroll
    for (int k = 0; k < 4; ++k) {
        int idx = k * 256 + t;
        int r = idx >> 4, c4 = idx & 15;
        int i = i0 + r;
        float4 val = (i < N_ROWS) ? A4[(size_t)i * M4 + (j0 >> 2) + c4]
                                  : make_float4(0.f, 0.f, 0.f, 0.f);
        tile[r][c4 * 4 + 0] = val.x;
        tile[r][c4 * 4 + 1] = val.y;
        tile[r][c4 * 4 + 2] = val.z;
        tile[r][c4 * 4 + 3] = val.w;
    }
    __syncthreads();
    half8* __restrict__ O8 = reinterpret_cast<half8*>(AT);
#pragma unroll
    for (int k = 0; k < 2; ++k) {
        int idx = k * 256 + t;          // 0..511 = 64 j x 8 q
        int j = idx >> 3, q = idx & 7;
        half8 h;
#pragma unroll
        for (int e = 0; e < 8; ++e) h[e] = (half_t)tile[q * 8 + e][j];
        O8[((size_t)(j0 + j) * NPAD + i0) / 8 + q] = h;
    }
}

// ---------------- fused PDHG x-pass + rank-1 (fp8) ----------------
__global__ __launch_bounds__(256) void k_fused8(const unsigned int* __restrict__ AT,
                                                const float* __restrict__ y,
                                                const float* __restrict__ c,
                                                const float* __restrict__ b,
                                                float* __restrict__ x,
                                                float* __restrict__ partial,
                                                const float* __restrict__ scalars) {
    __shared__ float yIn[4096];
    __shared__ float ypart[4096];
    const int tid = threadIdx.x;
    const int wv = tid >> 6, lane = tid & 63;
    {
        const float4* __restrict__ y4 = reinterpret_cast<const float4*>(y);
        float4* s4 = reinterpret_cast<float4*>(yIn);
#pragma unroll
        for (int k = 0; k < 4; ++k) s4[k * 256 + tid] = y4[k * 256 + tid];
    }
    __syncthreads();
    const float tau = scalars[1];
    const int j0 = blockIdx.x * FJ + wv * (FJ / 4);  // 8 cols per wave
    const uint2* __restrict__ A2 = reinterpret_cast<const uint2*>(AT);

    float xs = 0.f, cs = 0.f, bs = 0.f, xkeep = 0.f;
    if (lane < 8) {
        xs = x[j0 + lane];
        cs = c[j0 + lane];
        bs = b[j0 + lane];
    }

    float acc[64];
#pragma unroll
    for (int q = 0; q < 64; ++q) acc[q] = 0.f;

    uint2 cur[8], nxt[8];
#pragma unroll
    for (int p = 0; p < 8; ++p) cur[p] = A2[(size_t)j0 * 512 + p * 64 + lane];

    for (int q = 0; q < FJ / 4; ++q) {
        const int j = j0 + q;
        if (q + 1 < FJ / 4) {
#pragma unroll
            for (int p = 0; p < 8; ++p) nxt[p] = A2[(size_t)(j + 1) * 512 + p * 64 + lane];
        }
        float s = 0.f;
#pragma unroll
        for (int p = 0; p < 8; ++p) {
            float f[8];
            dec8(cur[p], f);
            const float4 ya = *reinterpret_cast<const float4*>(&yIn[p * 512 + lane * 4]);
            const float4 yb = *reinterpret_cast<const float4*>(&yIn[p * 512 + 256 + lane * 4]);
            s = fmaf(f[0], ya.x, s);
            s = fmaf(f[1], ya.y, s);
            s = fmaf(f[2], ya.z, s);
            s = fmaf(f[3], ya.w, s);
            s = fmaf(f[4], yb.x, s);
            s = fmaf(f[5], yb.y, s);
            s = fmaf(f[6], yb.z, s);
            s = fmaf(f[7], yb.w, s);
        }
#pragma unroll
        for (int o = 1; o < 64; o <<= 1) s += __shfl_xor(s, o, 64);
        s *= 0.015625f;                       // /64: values were 64*A
        float xo = __shfl(xs, q, 64);
        float cj = __shfl(cs, q, 64);
        float bj = __shfl(bs, q, 64);
        float xn = xo - tau * (cj + s);
        xn = fminf(fmaxf(xn, 0.f), bj);
        if (lane == q) xkeep = xn;
        float z = 2.f * xn - xo;
        // rank-1 in scaled units (64*A): merge applies tau/64
#pragma unroll
        for (int p = 0; p < 8; ++p) {
            float f[8];
            dec8(cur[p], f);
#pragma unroll
            for (int e = 0; e < 8; ++e)
                acc[p * 8 + e] = fmaf(f[e], z, acc[p * 8 + e]);
        }
#pragma unroll
        for (int p = 0; p < 8; ++p) cur[p] = nxt[p];
    }
    if (lane < 8) x[j0 + lane] = xkeep;

    for (int w = 0; w < 4; ++w) {
        if (wv == w) {
#pragma unroll
            for (int p = 0; p < 8; ++p) {
                float4* pa = reinterpret_cast<float4*>(&ypart[p * 512 + lane * 4]);
                float4* pb = reinterpret_cast<float4*>(&ypart[p * 512 + 256 + lane * 4]);
                float4 va = make_float4(acc[p * 8 + 0], acc[p * 8 + 1], acc[p * 8 + 2], acc[p * 8 + 3]);
                float4 vb = make_float4(acc[p * 8 + 4], acc[p * 8 + 5], acc[p * 8 + 6], acc[p * 8 + 7]);
                if (w == 0) { *pa = va; *pb = vb; }
                else {
                    float4 oa = *pa, ob = *pb;
                    oa.x += va.x; oa.y += va.y; oa.z += va.z; oa.w += va.w;
                    ob.x += vb.x; ob.y += vb.y; ob.z += vb.z; ob.w += vb.w;
                    *pa = oa; *pb = ob;
                }
            }
        }
        __syncthreads();
    }
    float4* __restrict__ P4 = reinterpret_cast<float4*>(partial + (size_t)blockIdx.x * 4096);
    const float4* __restrict__ S4 = reinterpret_cast<const float4*>(ypart);
#pragma unroll
    for (int k = 0; k < 4; ++k) P4[k * 256 + tid] = S4[k * 256 + tid];
}

// ---------------- parallel partial merge ----------------
// MODE 0: out = sum ; MODE 1: out += scalars[2] * sum   (scalars[2] = tau/64)
template <int MODE, int NP>
__global__ __launch_bounds__(256) void k_merge(const float* __restrict__ partial,
                                               float* __restrict__ out,
                                               const float* __restrict__ scalars) {
    constexpr int PER = NP / 16;
    const int tid = threadIdx.x;
    const int r = tid & 15, k = tid >> 4;
    const int row = blockIdx.x * 16 + r;
    const float* __restrict__ p0 = partial + (size_t)k * PER * NPAD + row;
    float s = 0.f;
#pragma unroll 8
    for (int q = 0; q < PER; ++q) s += p0[(size_t)q * NPAD];
    __shared__ float sm[256];
    sm[tid] = s;
    __syncthreads();
    if (tid < 16) {
        const int orow = blockIdx.x * 16 + tid;
        float tot = 0.f;
#pragma unroll
        for (int kk = 0; kk < 16; ++kk) tot += sm[kk * 16 + tid];
        if (MODE == 0) out[orow] = tot;
        else           out[orow] += scalars[2] * tot;
    }
}

// ---------------- power iter: w[j] = <AT8_j, u> (raw scaled) ----------------
__global__ __launch_bounds__(256) void k_colp8(const unsigned int* __restrict__ AT,
                                               const float* __restrict__ u,
                                               float* __restrict__ w) {
    const int wv = threadIdx.x >> 6, lane = threadIdx.x & 63;
    const int j = blockIdx.x * 4 + wv;
    const uint2* __restrict__ A2 = reinterpret_cast<const uint2*>(AT);
    const float4* __restrict__ u4 = reinterpret_cast<const float4*>(u);
    float s = 0.f;
#pragma unroll
    for (int p = 0; p < 8; ++p) {
        float f[8];
        dec8(A2[(size_t)j * 512 + p * 64 + lane], f);
        float4 ua = u4[p * 128 + lane];
        float4 ub = u4[p * 128 + 64 + lane];
        s = fmaf(f[0], ua.x, s);
        s = fmaf(f[1], ua.y, s);
        s = fmaf(f[2], ua.z, s);
        s = fmaf(f[3], ua.w, s);
        s = fmaf(f[4], ub.x, s);
        s = fmaf(f[5], ub.y, s);
        s = fmaf(f[6], ub.z, s);
        s = fmaf(f[7], ub.w, s);
    }
#pragma unroll
    for (int o = 1; o < 64; o <<= 1) s += __shfl_xor(s, o, 64);
    if (lane == 0) w[j] = s;
}

// ---------------- power iter: partial[ch][i] = sum_{j in ch} AT8[j][i]*v[j] ----------------
__global__ __launch_bounds__(256) void k_azp8(const unsigned int* __restrict__ AT,
                                              const float* __restrict__ zv,
                                              float* __restrict__ partial) {
    const int ch = blockIdx.y;
    const int j0 = ch * AZ_J;
    const int p = blockIdx.x * 256 + threadIdx.x;   // phys uint2 idx 0..511
    __shared__ float sz[AZ_J];
    if (threadIdx.x < AZ_J) sz[threadIdx.x] = zv[j0 + threadIdx.x];
    __syncthreads();
    const uint2* __restrict__ A2 = reinterpret_cast<const uint2*>(AT);
    float acc[8];
#pragma unroll
    for (int e = 0; e < 8; ++e) acc[e] = 0.f;
    for (int jj = 0; jj < AZ_J; ++jj) {
        float f[8];
        dec8(A2[(size_t)(j0 + jj) * 512 + p], f);
        float zj = sz[jj];
#pragma unroll
        for (int e = 0; e < 8; ++e) acc[e] = fmaf(f[e], zj, acc[e]);
    }
    const int ibase = (p >> 6) * 512 + (p & 63) * 4;
    float* __restrict__ P = partial + (size_t)ch * NPAD;
    *reinterpret_cast<float4*>(&P[ibase])       = make_float4(acc[0], acc[1], acc[2], acc[3]);
    *reinterpret_cast<float4*>(&P[ibase + 256]) = make_float4(acc[4], acc[5], acc[6], acc[7]);
}

// ---------------- final polish: fp16 column dot + x-update (round-3 k_col) ----------------
template <int MODE>
__global__ __launch_bounds__(256) void k_col(const half_t* __restrict__ AT,
                                             const float* __restrict__ u,
                                             const float* __restrict__ c,
                                             const float* __restrict__ b,
                                             float* __restrict__ x,
                                             float* __restrict__ z,
                                             float* __restrict__ w,
                                             const float* __restrict__ scalars) {
    const int wv   = threadIdx.x >> 6;
    const int lane = threadIdx.x & 63;
    const int j = blockIdx.x * 4 + wv;
    const half8* __restrict__ row = reinterpret_cast<const half8*>(AT + (size_t)j * NPAD);
    const float4* __restrict__ u4 = reinterpret_cast<const float4*>(u);
    float s = 0.f;
#pragma unroll
    for (int it = 0; it < NPAD / 8 / 64; ++it) {
        int k = it * 64 + lane;
        half8 a = row[k];
        float4 ua = u4[2 * k];
        float4 ub = u4[2 * k + 1];
        s = fmaf((float)a[0], ua.x, s);
        s = fmaf((float)a[1], ua.y, s);
        s = fmaf((float)a[2], ua.z, s);
        s = fmaf((float)a[3], ua.w, s);
        s = fmaf((float)a[4], ub.x, s);
        s = fmaf((float)a[5], ub.y, s);
        s = fmaf((float)a[6], ub.z, s);
        s = fmaf((float)a[7], ub.w, s);
    }
#pragma unroll
    for (int o = 1; o < 64; o <<= 1) s += __shfl_xor(s, o, 64);
    if (lane == 0) {
        if (MODE == 0) {
            w[j] = s;
        } else {
            float tau = scalars[1];
            float xo = x[j];
            float xn = xo - tau * (c[j] + s);
            xn = fminf(fmaxf(xn, 0.f), b[j]);
            x[j] = xn;
            z[j] = 2.f * xn - xo;
        }
    }
}

// ================= fp32 fallback kernels (round-1 verified) =================
__global__ __launch_bounds__(256) void k_at_partial(const float* __restrict__ A,
                                                    const float* __restrict__ u,
                                                    float* __restrict__ partial) {
    const int j4 = blockIdx.x * 256 + threadIdx.x;
    const int r0 = blockIdx.y * ROWS_PER_CHUNK;
    const int r1 = min(r0 + ROWS_PER_CHUNK, N_ROWS);
    __shared__ float su[ROWS_PER_CHUNK];
    if (threadIdx.x < (unsigned)(r1 - r0)) su[threadIdx.x] = u[r0 + threadIdx.x];
    __syncthreads();
    const float4* __restrict__ A4 = reinterpret_cast<const float4*>(A);
    float4 acc = make_float4(0.f, 0.f, 0.f, 0.f);
    for (int i = r0; i < r1; ++i) {
        const float ui = su[i - r0];
        float4 a = A4[(size_t)i * M4 + j4];
        acc.x = fmaf(a.x, ui, acc.x);
        acc.y = fmaf(a.y, ui, acc.y);
        acc.z = fmaf(a.z, ui, acc.z);
        acc.w = fmaf(a.w, ui, acc.w);
    }
    reinterpret_cast<float4*>(partial)[(size_t)blockIdx.y * M4 + j4] = acc;
}

__global__ __launch_bounds__(256) void k_reduce_w(const float* __restrict__ partial,
                                                  float* __restrict__ w) {
    int j = blockIdx.x * 256 + threadIdx.x;
    float s = 0.f;
    for (int p = 0; p < P_CHUNKS; ++p) s += partial[(size_t)p * M_COLS + j];
    w[j] = s;
}

__global__ __launch_bounds__(256) void k_x_update(const float* __restrict__ partial,
                                                  const float* __restrict__ c,
                                                  const float* __restrict__ b,
                                                  float* __restrict__ x,
                                                  float* __restrict__ z,
                                                  const float* __restrict__ scalars) {
    int j = blockIdx.x * 256 + threadIdx.x;
    const float tau = scalars[1];
    float s = 0.f;
    for (int p = 0; p < P_CHUNKS; ++p) s += partial[(size_t)p * M_COLS + j];
    float xo = x[j];
    float xn = xo - tau * (c[j] + s);
    xn = fminf(fmaxf(xn, 0.f), b[j]);
    x[j] = xn;
    z[j] = 2.f * xn - xo;
}

template <int MODE>
__global__ __launch_bounds__(256) void k_row_dot(const float* __restrict__ A,
                                                 const float* __restrict__ vec,
                                                 float* __restrict__ out,
                                                 const float* __restrict__ scalars) {
    const int i = blockIdx.x;
    const float4* __restrict__ row = reinterpret_cast<const float4*>(A + (size_t)i * M_COLS);
    const float4* __restrict__ v4  = reinterpret_cast<const float4*>(vec);
    float s = 0.f;
    for (int k = threadIdx.x; k < M4; k += 256) {
        float4 a = row[k];
        float4 v = v4[k];
        s = fmaf(a.x, v.x, s);
        s = fmaf(a.y, v.y, s);
        s = fmaf(a.z, v.z, s);
        s = fmaf(a.w, v.w, s);
    }
    for (int o = 32; o > 0; o >>= 1) s += __shfl_down(s, o, 64);
    __shared__ float sm[4];
    if ((threadIdx.x & 63) == 0) sm[threadIdx.x >> 6] = s;
    __syncthreads();
    if (threadIdx.x == 0) {
        float t = sm[0] + sm[1] + sm[2] + sm[3];
        if (MODE == 0) out[i] = t;
        else           out[i] += scalars[1] * t;
    }
}

// ---------------- norms ----------------
// MODE 0: scalars[0] = ||w||   (any scale; used only for normalize)
// MODE 1: fp8-scaled: w = 4096*A^T A v -> tau = 57.6/sqrt(||w||); scalars[2]=tau/64
// MODE 2: true-scale (fp32 fallback): tau = 0.9/sqrt(||w||)
template <int MODE>
__global__ __launch_bounds__(1024) void k_norm(const float* __restrict__ w,
                                               float* __restrict__ scalars) {
    const float4* __restrict__ w4 = reinterpret_cast<const float4*>(w);
    float s = 0.f;
    for (int k = threadIdx.x; k < M4; k += 1024) {
        float4 a = w4[k];
        s = fmaf(a.x, a.x, s);
        s = fmaf(a.y, a.y, s);
        s = fmaf(a.z, a.z, s);
        s = fmaf(a.w, a.w, s);
    }
    for (int o = 32; o > 0; o >>= 1) s += __shfl_down(s, o, 64);
    __shared__ float sm[16];
    if ((threadIdx.x & 63) == 0) sm[threadIdx.x >> 6] = s;
    __syncthreads();
    if (threadIdx.x == 0) {
        float t = 0.f;
        for (int q = 0; q < 16; ++q) t += sm[q];
        float nrm = sqrtf(t);               // ||w||
        if (MODE == 0) scalars[0] = nrm;
        else if (MODE == 1) {
            float tau = 57.6f / sqrtf(nrm); // 0.9*64/sqrt(||w||_meas)
            scalars[1] = tau;
            scalars[2] = tau * 0.015625f;
        } else {
            scalars[1] = 0.9f / sqrtf(nrm);
        }
    }
}

__global__ __launch_bounds__(256) void k_scale(const float* __restrict__ w,
                                               float* __restrict__ v,
                                               const float* __restrict__ scalars) {
    int j = blockIdx.x * 256 + threadIdx.x;
    v[j] = w[j] / scalars[0];
}

__global__ __launch_bounds__(1024) void k_obj(const float* __restrict__ x,
                                              const float* __restrict__ c,
                                              float* __restrict__ out) {
    float s = 0.f;
    for (int k = threadIdx.x; k < M_COLS; k += 1024) s = fmaf(x[k], -c[k], s);
    for (int o = 32; o > 0; o >>= 1) s += __shfl_down(s, o, 64);
    __shared__ float sm[16];
    if ((threadIdx.x & 63) == 0) sm[threadIdx.x >> 6] = s;
    __syncthreads();
    if (threadIdx.x == 0) {
        float t = 0.f;
        for (int q = 0; q < 16; ++q) t += sm[q];
        out[0] = t;
    }
}

extern "C" void kernel_launch(void* const* d_in, const int* in_sizes, int n_in,
                              void* d_out, int out_size, void* d_ws, size_t ws_size,
                              hipStream_t stream) {
    const float* A = (const float*)d_in[0];
    const float* b = (const float*)d_in[1];
    const float* c = (const float*)d_in[2];
    float* out = (float*)d_out;

    float* ws = (float*)d_ws;
    float* x       = ws;                        // M
    float* z       = x + M_COLS;                // M
    float* v       = z + M_COLS;                // M
    float* w       = v + M_COLS;                // M
    float* y       = w + M_COLS;                // NPAD
    float* t       = y + NPAD;                  // NPAD
    float* scalars = t + NPAD;                  // 16
    float* partial = scalars + 16;              // 8 MB region

    size_t partial_floats = (size_t)2 * 1024 * 1024;  // max(512*4096, 256*4096, 64*16384)
    size_t base = (size_t)(partial - ws) * 4 + partial_floats * 4;
    size_t a8_off = (base + 255) & ~(size_t)255;
    unsigned int* AT8 = (unsigned int*)((char*)d_ws + a8_off);
    size_t a8_bytes = (size_t)M_COLS * NPAD;                  // 64 MB
    size_t a16_off = (a8_off + a8_bytes + 255) & ~(size_t)255;
    half_t* AT16 = (half_t*)((char*)d_ws + a16_off);
    size_t a16_bytes = (size_t)M_COLS * NPAD * sizeof(half_t); // 134.2 MB
    size_t need_full = a16_off + a16_bytes;                    // ~207 MB
    size_t need_fp32 = (size_t)(partial - ws) * 4 + (size_t)P_CHUNKS * M_COLS * 4;

    dim3 b256(256);
    dim3 gM(M_COLS / 256);            // 64
    dim3 gCol(M_COLS / 4);            // 4096
    dim3 gFused(FBLOCKS);             // 512
    dim3 gAz(NPAD / 8 / 256, AZ_CH);  // (2, 256)
    dim3 gMerge(NPAD / 16);           // 256
    dim3 gRowA(N_ROWS);
    dim3 gTr(NPAD / 64, M_COLS / 64); // (64, 256)

    k_init<<<gM, b256, 0, stream>>>(x, v, y, t);

    if (ws_size >= need_full) {
        // ======== fp8 path with fp16 final polish ========
        k_transpose8<<<gTr, b256, 0, stream>>>(A, AT8);
        k_transpose16<<<gTr, b256, 0, stream>>>(A, AT16);

        for (int it = 0; it < POWER_ITERS; ++it) {
            k_azp8<<<gAz, b256, 0, stream>>>(AT8, v, partial);                 // 64*Av chunks
            k_merge<0, AZ_CH><<<gMerge, b256, 0, stream>>>(partial, t, scalars); // t = 64*Av
            k_colp8<<<gCol, b256, 0, stream>>>(AT8, t, w);                     // w = 4096*A^TAv
            k_norm<0><<<1, 1024, 0, stream>>>(w, scalars);
            k_scale<<<gM, b256, 0, stream>>>(w, v, scalars);                   // v unit
        }
        k_azp8<<<gAz, b256, 0, stream>>>(AT8, v, partial);
        k_merge<0, AZ_CH><<<gMerge, b256, 0, stream>>>(partial, t, scalars);
        k_colp8<<<gCol, b256, 0, stream>>>(AT8, t, w);
        k_norm<1><<<1, 1024, 0, stream>>>(w, scalars);                         // tau, tau/64

        for (int it = 0; it < PDHG_ITERS - 1; ++it) {
            k_fused8<<<gFused, b256, 0, stream>>>(AT8, y, c, b, x, partial, scalars);
            k_merge<1, FBLOCKS><<<gMerge, b256, 0, stream>>>(partial, y, scalars);
        }
        // final x-step (its y-half is unused by the output) in fp16
        k_col<1><<<gCol, b256, 0, stream>>>(AT16, y, c, b, x, z, w, scalars);
    } else if (ws_size >= need_fp32) {
        // ======== fp32 fallback ========
        dim3 gAt(M4 / 256, P_CHUNKS);
        for (int it = 0; it < POWER_ITERS; ++it) {
            k_row_dot<0><<<gRowA, b256, 0, stream>>>(A, v, t, scalars);
            k_at_partial<<<gAt, b256, 0, stream>>>(A, t, partial);
            k_reduce_w<<<gM, b256, 0, stream>>>(partial, w);
            k_norm<0><<<1, 1024, 0, stream>>>(w, scalars);
            k_scale<<<gM, b256, 0, stream>>>(w, v, scalars);
        }
        k_row_dot<0><<<gRowA, b256, 0, stream>>>(A, v, t, scalars);
        k_at_partial<<<gAt, b256, 0, stream>>>(A, t, partial);
        k_reduce_w<<<gM, b256, 0, stream>>>(partial, w);
        k_norm<2><<<1, 1024, 0, stream>>>(w, scalars);
        for (int it = 0; it < PDHG_ITERS; ++it) {
            k_at_partial<<<gAt, b256, 0, stream>>>(A, y, partial);
            k_x_update<<<gM, b256, 0, stream>>>(partial, c, b, x, z, scalars);
            k_row_dot<1><<<gRowA, b256, 0, stream>>>(A, z, y, scalars);
        }
    }

    k_obj<<<1, 1024, 0, stream>>>(x, c, out);
}